// Round 3
// baseline (167.424 us; speedup 1.0000x reference)
//
#include <hip/hip_runtime.h>

#define N 2048
#define T 32
#define D 128
#define BT 32
#define MT (N / BT)                // 64 row-blocks
#define NTILES (MT * (MT + 1) / 2) // 2080 upper-triangular 32x32 tiles
#define NWAVES (2 * NTILES)        // 4160 half-tile (16x32) single-wave blocks
#define PSTR 33                    // LDS row stride (32 data + 1)

typedef float floatx4 __attribute__((ext_vector_type(4)));
typedef short bf16x8 __attribute__((ext_vector_type(8)));

// s_waitcnt lgkmcnt(0) only — 0xc07f. Single-wave WG: no barrier ever.
#define LGKM0() __builtin_amdgcn_s_waitcnt(0xc07f)

// tile id -> (a,b), a<=b, upper-triangular over MT x MT
__device__ __forceinline__ void tile_decode(int t, int& a, int& b) {
  a = (int)((2 * MT + 1 -
             sqrtf((float)((2 * MT + 1) * (2 * MT + 1) - 8 * t))) * 0.5f);
  while (a > 0 && t < a * MT - a * (a - 1) / 2) --a;
  while (t >= (a + 1) * MT - (a + 1) * a / 2) ++a;
  b = a + (t - (a * MT - a * (a - 1) / 2));
}

// ---------------------------------------------------------------------------
// Kernel 1: normalize each X row, split into truncated-bf16 h/l planes
// (xn = h + l + eps, hh+hl+lh Gram error <= 2^-16 rel — absmax 0.0 in R7),
// and store in MFMA-TILED layout:
//   plane[rb*2048 + ks*512 + q*128 + m*8 + j]  (shorts)
// so a pair-kernel fragment load (lanes = (m,q)) is one fully-coalesced
// 1 KB wave-read. One 64-thread wave per 16-row block; lane (m,q) owns row
// 16rb+m, cols {q*8 + ks*32}. Block 0 also zeroes the done-ticket counter
// (visible to pair_kernel via the kernel-boundary release).
// ---------------------------------------------------------------------------
__global__ __launch_bounds__(64) void presplit_kernel(
    const float* __restrict__ X, unsigned short* __restrict__ hXt,
    unsigned short* __restrict__ lXt, unsigned int* __restrict__ done_ctr) {
  const int rb   = blockIdx.x;          // 0..127
  const int lane = threadIdx.x;
  const int m    = lane & 15;
  const int q    = lane >> 4;

  if (rb == 0 && lane == 0) *done_ctr = 0;

  const float* xr = X + (size_t)(16 * rb + m) * D + q * 8;
  float4 v0[4], v1[4];
  float ss = 0.0f;
#pragma unroll
  for (int ks = 0; ks < 4; ++ks) {
    v0[ks] = *(const float4*)(xr + ks * 32);
    v1[ks] = *(const float4*)(xr + ks * 32 + 4);
    ss += v0[ks].x * v0[ks].x + v0[ks].y * v0[ks].y +
          v0[ks].z * v0[ks].z + v0[ks].w * v0[ks].w +
          v1[ks].x * v1[ks].x + v1[ks].y * v1[ks].y +
          v1[ks].z * v1[ks].z + v1[ks].w * v1[ks].w;
  }
  // row sumsq: lanes m, m+16, m+32, m+48 hold the 4 col-quads of row m
  ss += __shfl_xor(ss, 16, 64);
  ss += __shfl_xor(ss, 32, 64);
  const float rn = rsqrtf(ss);

#pragma unroll
  for (int ks = 0; ks < 4; ++ks) {
    bf16x8 h, l;
    float v[8] = {v0[ks].x, v0[ks].y, v0[ks].z, v0[ks].w,
                  v1[ks].x, v1[ks].y, v1[ks].z, v1[ks].w};
#pragma unroll
    for (int i = 0; i < 8; ++i) {
      const float a = v[i] * rn;
      const unsigned u = __float_as_uint(a);
      h[i] = (short)(u >> 16);
      const float lo = a - __uint_as_float(u & 0xffff0000u);  // exact
      l[i] = (short)(__float_as_uint(lo) >> 16);
    }
    const size_t o = (size_t)rb * 2048 + ks * 512 + q * 128 + m * 8;
    *(bf16x8*)(hXt + o) = h;
    *(bf16x8*)(lXt + o) = l;
  }
}

// ---------------------------------------------------------------------------
// Kernel 2 (R12): exact R9 half-tile structure (best measured: 80.46) with
// the finalize fused in via last-WG-done ticket. Each WG: one 16x32
// half-tile, single wave, per-WG partial store (no hot-path atomics — R8).
// Lane 0 then does one device-scope ACQ_REL fetch_add; the WG drawing the
// last ticket fences and reduces all 4160 partials with 4 independent
// accumulators (pipelined loads), writes the final result. Removes the
// finalize dispatch + its serial single-WG latency.
// ---------------------------------------------------------------------------
__global__ __launch_bounds__(64) void pair_kernel(
    const float* __restrict__ pred,          // [N][T]
    const unsigned short* __restrict__ hXt,  // tiled bf16 high plane
    const unsigned short* __restrict__ lXt,  // tiled bf16 low plane
    const float* __restrict__ scale_p,       // [1]
    double* __restrict__ partials,           // [NWAVES]
    unsigned int* __restrict__ done_ctr,     // [1], zeroed by presplit
    const float* __restrict__ target,        // [1]
    float* __restrict__ out) {               // [1]
  __shared__ float P[48 * PSTR];             // 16 A-pred rows + 32 B-pred rows

  const int lane = threadIdx.x;
  const int w    = blockIdx.x;
  const int tile = w >> 1;
  const int h    = w & 1;                    // half: A-rows 16h..16h+15

  int a, b;
  tile_decode(tile, a, b);
  const int aRow0 = a * BT, bRow0 = b * BT;
  const int m    = lane & 15;
  const int quad = lane >> 4;
  const float scale = scale_p[0];

  // ---- stage 48 pred rows: 384 float4 chunks / 64 lanes = 6 each
#pragma unroll
  for (int s = 0; s < 6; ++s) {
    const int idx = s * 64 + lane;
    const int row = idx >> 3;
    const int fo  = (idx & 7) * 4;
    const int grow = (row < 16) ? (aRow0 + 16 * h + row) : (bRow0 + row - 16);
    *(float4*)(&P[row * PSTR + fo]) =
        *(const float4*)(pred + (size_t)grow * T + fo);
  }

  // ---- Gram half-tile via split-bf16 MFMA, tiled coalesced fragment loads
  floatx4 accf[2];
  accf[0] = (floatx4){0.f, 0.f, 0.f, 0.f};
  accf[1] = (floatx4){0.f, 0.f, 0.f, 0.f};

  const int arb = aRow0 / 16 + h;            // A 16-row block
  const int brb = bRow0 / 16;                // B 16-row blocks: brb, brb+1
  const size_t fo2 = (size_t)quad * 128 + m * 8;
  const unsigned short* pa_h = hXt + (size_t)arb * 2048 + fo2;
  const unsigned short* pa_l = lXt + (size_t)arb * 2048 + fo2;
  const unsigned short* pb_h = hXt + (size_t)brb * 2048 + fo2;
  const unsigned short* pb_l = lXt + (size_t)brb * 2048 + fo2;

#pragma unroll
  for (int ks = 0; ks < 4; ++ks) {
    bf16x8 hA, lA, hB[2], lB[2];
    hA = *(const bf16x8*)(pa_h + ks * 512);
    lA = *(const bf16x8*)(pa_l + ks * 512);
#pragma unroll
    for (int J = 0; J < 2; ++J) {
      hB[J] = *(const bf16x8*)(pb_h + (size_t)J * 2048 + ks * 512);
      lB[J] = *(const bf16x8*)(pb_l + (size_t)J * 2048 + ks * 512);
    }
#pragma unroll
    for (int J = 0; J < 2; ++J) {
      accf[J] = __builtin_amdgcn_mfma_f32_16x16x32_bf16(hA, hB[J], accf[J], 0, 0, 0);
      accf[J] = __builtin_amdgcn_mfma_f32_16x16x32_bf16(hA, lB[J], accf[J], 0, 0, 0);
      accf[J] = __builtin_amdgcn_mfma_f32_16x16x32_bf16(lA, hB[J], accf[J], 0, 0, 0);
    }
  }

  // ---- sd = scale*(1 - G); C layout: row = quad*4+r, col = 16J+m
  float sd[2][4], ps[2][4];
#pragma unroll
  for (int J = 0; J < 2; ++J)
#pragma unroll
    for (int r = 0; r < 4; ++r) {
      sd[J][r] = scale * (1.0f - accf[J][r]);
      ps[J][r] = 0.0f;
    }
  LGKM0();  // pred staging visible (single wave: DS in-order)

  // ---- hinge: sum_t max(|dp|, s); -32s correction under the mask
#pragma unroll
  for (int t4 = 0; t4 < 8; ++t4) {
    float4 qb[2];
    qb[0] = *(const float4*)(&P[(16 + m) * PSTR + t4 * 4]);
    qb[1] = *(const float4*)(&P[(32 + m) * PSTR + t4 * 4]);
#pragma unroll
    for (int r = 0; r < 4; ++r) {
      float4 qa = *(const float4*)(&P[(quad * 4 + r) * PSTR + t4 * 4]);
#pragma unroll
      for (int J = 0; J < 2; ++J) {
        float s = sd[J][r];
        ps[J][r] += fmaxf(fabsf(qa.x - qb[J].x), s) +
                    fmaxf(fabsf(qa.y - qb[J].y), s) +
                    fmaxf(fabsf(qa.z - qb[J].z), s) +
                    fmaxf(fabsf(qa.w - qb[J].w), s);
      }
    }
  }

  // ---- mask + correction + wave reduction
  float tsum = 0.0f;
#pragma unroll
  for (int J = 0; J < 2; ++J)
#pragma unroll
    for (int r = 0; r < 4; ++r) {
      const int ja   = aRow0 + 16 * h + quad * 4 + r;
      const int kcol = bRow0 + 16 * J + m;
      tsum += (kcol > ja) ? (ps[J][r] - 32.0f * sd[J][r]) : 0.0f;
    }

  double dsum = (double)tsum;
#pragma unroll
  for (int off = 32; off > 0; off >>= 1) dsum += __shfl_down(dsum, off, 64);

  // ---- fused finalize: last-WG-done ticket (rocPRIM pattern)
  int islast = 0;
  if (lane == 0) {
    partials[w] = dsum;
    const unsigned t = __hip_atomic_fetch_add(
        done_ctr, 1u, __ATOMIC_ACQ_REL, __HIP_MEMORY_SCOPE_AGENT);
    islast = (t == NWAVES - 1);
  }
  islast = __shfl(islast, 0, 64);
  if (islast) {
    __threadfence();  // acquire: other WGs' partials visible to all lanes
    // 4160 = 16*256 + 64; 4 independent accumulators keep loads in flight
    double a0 = 0.0, a1 = 0.0, a2 = 0.0, a3 = 0.0;
    for (int i = lane; i < 4096; i += 256) {
      a0 += partials[i];
      a1 += partials[i + 64];
      a2 += partials[i + 128];
      a3 += partials[i + 192];
    }
    a0 += partials[4096 + lane];
    double s = (a0 + a1) + (a2 + a3);
#pragma unroll
    for (int off = 32; off > 0; off >>= 1) s += __shfl_down(s, off, 64);
    if (lane == 0) {
      const double mf = 2.0 * s / ((double)N * (double)(N - 1) * (double)T);
      const double r  = mf - (double)target[0];
      out[0] = (float)(r > 0.0 ? r : 0.0);
    }
  }
}

extern "C" void kernel_launch(void* const* d_in, const int* in_sizes, int n_in,
                              void* d_out, int out_size, void* d_ws, size_t ws_size,
                              hipStream_t stream) {
  const float* target = (const float*)d_in[0];
  const float* pred   = (const float*)d_in[1];
  const float* X      = (const float*)d_in[2];
  // d_in[3] = ntimes (==32, hardcoded); d_in[4] = scale
  const float* scale  = (const float*)d_in[4];

  double*       partials = (double*)d_ws;                               // 33 KB
  unsigned int* done_ctr = (unsigned int*)((char*)d_ws + (512u << 10)); // 4 B
  unsigned short* hXt = (unsigned short*)((char*)d_ws + (1u << 20));    // 512 KB
  unsigned short* lXt = (unsigned short*)((char*)d_ws + (2u << 20));    // 512 KB

  presplit_kernel<<<dim3(D), dim3(64), 0, stream>>>(X, hXt, lXt, done_ctr);
  pair_kernel<<<dim3(NWAVES), dim3(64), 0, stream>>>(pred, hXt, lXt, scale,
                                                     partials, done_ctr,
                                                     target, (float*)d_out);
}

// Round 4
// 82.233 us; speedup vs baseline: 2.0360x; 2.0360x over previous
//
#include <hip/hip_runtime.h>

#define N 2048
#define T 32
#define D 128
#define BT 32
#define MT (N / BT)                // 64 row-blocks
#define NTILES (MT * (MT + 1) / 2) // 2080 upper-triangular 32x32 tiles
#define NWAVES (2 * NTILES)        // 4160 half-tile (16x32) single-wave blocks

typedef float floatx4 __attribute__((ext_vector_type(4)));
typedef short bf16x8 __attribute__((ext_vector_type(8)));

// direct global->LDS 16B copy: dest = readfirstlane(lds) + lane*16 (linear)
__device__ __forceinline__ void gload_lds16(const float* g, float* l) {
  __builtin_amdgcn_global_load_lds(
      (const __attribute__((address_space(1))) void*)g,
      (__attribute__((address_space(3))) void*)l, 16, 0, 0);
}

// tile id -> (a,b), a<=b, upper-triangular over MT x MT
__device__ __forceinline__ void tile_decode(int t, int& a, int& b) {
  a = (int)((2 * MT + 1 -
             sqrtf((float)((2 * MT + 1) * (2 * MT + 1) - 8 * t))) * 0.5f);
  while (a > 0 && t < a * MT - a * (a - 1) / 2) --a;
  while (t >= (a + 1) * MT - (a + 1) * a / 2) ++a;
  b = a + (t - (a * MT - a * (a - 1) / 2));
}

// ---------------------------------------------------------------------------
// Kernel 1: normalize each X row, split into truncated-bf16 h/l planes
// (xn = h + l + eps, hh+hl+lh Gram error <= 2^-16 rel — absmax 0.0 in R7),
// and store in MFMA-TILED layout:
//   plane[rb*2048 + ks*512 + q*128 + m*8 + j]  (shorts)
// so a pair-kernel fragment load (lanes = (m,q)) is one fully-coalesced
// 1 KB wave-read. One 64-thread wave per 16-row block; lane (m,q) owns row
// 16rb+m, cols {q*8 + ks*32}.
// ---------------------------------------------------------------------------
__global__ __launch_bounds__(64) void presplit_kernel(
    const float* __restrict__ X, unsigned short* __restrict__ hXt,
    unsigned short* __restrict__ lXt) {
  const int rb   = blockIdx.x;          // 0..127
  const int lane = threadIdx.x;
  const int m    = lane & 15;
  const int q    = lane >> 4;

  const float* xr = X + (size_t)(16 * rb + m) * D + q * 8;
  float4 v0[4], v1[4];
  float ss = 0.0f;
#pragma unroll
  for (int ks = 0; ks < 4; ++ks) {
    v0[ks] = *(const float4*)(xr + ks * 32);
    v1[ks] = *(const float4*)(xr + ks * 32 + 4);
    ss += v0[ks].x * v0[ks].x + v0[ks].y * v0[ks].y +
          v0[ks].z * v0[ks].z + v0[ks].w * v0[ks].w +
          v1[ks].x * v1[ks].x + v1[ks].y * v1[ks].y +
          v1[ks].z * v1[ks].z + v1[ks].w * v1[ks].w;
  }
  // row sumsq: lanes m, m+16, m+32, m+48 hold the 4 col-quads of row m
  ss += __shfl_xor(ss, 16, 64);
  ss += __shfl_xor(ss, 32, 64);
  const float rn = rsqrtf(ss);

#pragma unroll
  for (int ks = 0; ks < 4; ++ks) {
    bf16x8 h, l;
    float v[8] = {v0[ks].x, v0[ks].y, v0[ks].z, v0[ks].w,
                  v1[ks].x, v1[ks].y, v1[ks].z, v1[ks].w};
#pragma unroll
    for (int i = 0; i < 8; ++i) {
      const float a = v[i] * rn;
      const unsigned u = __float_as_uint(a);
      h[i] = (short)(u >> 16);
      const float lo = a - __uint_as_float(u & 0xffff0000u);  // exact
      l[i] = (short)(__float_as_uint(lo) >> 16);
    }
    const size_t o = (size_t)rb * 2048 + ks * 512 + q * 128 + m * 8;
    *(bf16x8*)(hXt + o) = h;
    *(bf16x8*)(lXt + o) = l;
  }
}

// ---------------------------------------------------------------------------
// Kernel 2 (R13): exact R9 half-tile structure (best measured: 80.46) with
// the pred staging converted to direct global->LDS DMA:
//   - 6x global_load_lds(16B) issued FIRST (no VGPR round-trip, no ds_write),
//     drained by a single s_waitcnt vmcnt(0) after the MFMA section, so the
//     whole Gram phase hides staging latency (was: load->vmcnt->ds_write->
//     lgkm serial chain per wave).
//   - global_load_lds needs a LINEAR LDS dest, so P is contiguous [48][32]
//     with an XOR chunk swizzle (chunk' = chunk ^ (row&7)) applied on the
//     per-lane GLOBAL source address (m173 pattern) and on LDS reads.
//     Bank math: qa reads 2-way (free), qb reads spread 32 banks at 2-way.
// Finalize back to its own kernel — R12's fused device-scope ticket atomic
// cost ~80 us in XCD cache-line ping-pong + cache maintenance. Per-WG
// partials to distinct addresses (no atomics anywhere in the hot path).
// ---------------------------------------------------------------------------
__global__ __launch_bounds__(64) void pair_kernel(
    const float* __restrict__ pred,          // [N][T]
    const unsigned short* __restrict__ hXt,  // tiled bf16 high plane
    const unsigned short* __restrict__ lXt,  // tiled bf16 low plane
    const float* __restrict__ scale_p,       // [1]
    double* __restrict__ partials) {         // [NWAVES]
  __shared__ float P[48 * 32];               // linear; XOR-swizzled chunks

  const int lane = threadIdx.x;
  const int w    = blockIdx.x;
  const int tile = w >> 1;
  const int h    = w & 1;                    // half: A-rows 16h..16h+15

  int a, b;
  tile_decode(tile, a, b);
  const int aRow0 = a * BT, bRow0 = b * BT;
  const int m    = lane & 15;
  const int quad = lane >> 4;
  const float scale = scale_p[0];

  // ---- stage 48 pred rows: 384 16B chunks / 64 lanes = 6 global_load_lds.
  // LDS slot idx = s*64+lane = row*8+c holds global chunk c^(row&7) of grow.
#pragma unroll
  for (int s = 0; s < 6; ++s) {
    const int idx = s * 64 + lane;
    const int row = idx >> 3;
    const int cc  = (idx & 7) ^ (row & 7);   // pre-swizzled global source
    const int grow = (row < 16) ? (aRow0 + 16 * h + row) : (bRow0 + row - 16);
    gload_lds16(pred + (size_t)grow * T + cc * 4, &P[s * 256]);
  }

  // ---- Gram half-tile via split-bf16 MFMA, tiled coalesced fragment loads
  floatx4 accf[2];
  accf[0] = (floatx4){0.f, 0.f, 0.f, 0.f};
  accf[1] = (floatx4){0.f, 0.f, 0.f, 0.f};

  const int arb = aRow0 / 16 + h;            // A 16-row block
  const int brb = bRow0 / 16;                // B 16-row blocks: brb, brb+1
  const size_t fo2 = (size_t)quad * 128 + m * 8;
  const unsigned short* pa_h = hXt + (size_t)arb * 2048 + fo2;
  const unsigned short* pa_l = lXt + (size_t)arb * 2048 + fo2;
  const unsigned short* pb_h = hXt + (size_t)brb * 2048 + fo2;
  const unsigned short* pb_l = lXt + (size_t)brb * 2048 + fo2;

#pragma unroll
  for (int ks = 0; ks < 4; ++ks) {
    bf16x8 hA, lA, hB[2], lB[2];
    hA = *(const bf16x8*)(pa_h + ks * 512);
    lA = *(const bf16x8*)(pa_l + ks * 512);
#pragma unroll
    for (int J = 0; J < 2; ++J) {
      hB[J] = *(const bf16x8*)(pb_h + (size_t)J * 2048 + ks * 512);
      lB[J] = *(const bf16x8*)(pb_l + (size_t)J * 2048 + ks * 512);
    }
#pragma unroll
    for (int J = 0; J < 2; ++J) {
      accf[J] = __builtin_amdgcn_mfma_f32_16x16x32_bf16(hA, hB[J], accf[J], 0, 0, 0);
      accf[J] = __builtin_amdgcn_mfma_f32_16x16x32_bf16(hA, lB[J], accf[J], 0, 0, 0);
      accf[J] = __builtin_amdgcn_mfma_f32_16x16x32_bf16(lA, hB[J], accf[J], 0, 0, 0);
    }
  }

  // ---- sd = scale*(1 - G); C layout: row = quad*4+r, col = 16J+m
  float sd[2][4], ps[2][4];
#pragma unroll
  for (int J = 0; J < 2; ++J)
#pragma unroll
    for (int r = 0; r < 4; ++r) {
      sd[J][r] = scale * (1.0f - accf[J][r]);
      ps[J][r] = 0.0f;
    }

  // drain the 6 global_load_lds (oldest vmem ops; fragment waits mostly
  // drained them already). Single wave per WG: no barrier needed.
  asm volatile("s_waitcnt vmcnt(0)" ::: "memory");

  // ---- hinge: sum_t max(|dp|, s); -32s correction under the mask.
  // Swizzled read: chunk t4 of row lives at P[row*32 + ((t4^(row&7))<<2)].
#pragma unroll
  for (int t4 = 0; t4 < 8; ++t4) {
    float4 qb[2];
    qb[0] = *(const float4*)(&P[(16 + m) * 32 + ((t4 ^ (m & 7)) << 2)]);
    qb[1] = *(const float4*)(&P[(32 + m) * 32 + ((t4 ^ (m & 7)) << 2)]);
#pragma unroll
    for (int r = 0; r < 4; ++r) {
      const int ra = quad * 4 + r;
      float4 qa = *(const float4*)(&P[ra * 32 + ((t4 ^ (ra & 7)) << 2)]);
#pragma unroll
      for (int J = 0; J < 2; ++J) {
        float s = sd[J][r];
        ps[J][r] += fmaxf(fabsf(qa.x - qb[J].x), s) +
                    fmaxf(fabsf(qa.y - qb[J].y), s) +
                    fmaxf(fabsf(qa.z - qb[J].z), s) +
                    fmaxf(fabsf(qa.w - qb[J].w), s);
      }
    }
  }

  // ---- mask + correction + wave reduction
  float tsum = 0.0f;
#pragma unroll
  for (int J = 0; J < 2; ++J)
#pragma unroll
    for (int r = 0; r < 4; ++r) {
      const int ja   = aRow0 + 16 * h + quad * 4 + r;
      const int kcol = bRow0 + 16 * J + m;
      tsum += (kcol > ja) ? (ps[J][r] - 32.0f * sd[J][r]) : 0.0f;
    }

  double dsum = (double)tsum;
#pragma unroll
  for (int off = 32; off > 0; off >>= 1) dsum += __shfl_down(dsum, off, 64);
  if (lane == 0) partials[w] = dsum;
}

// ---------------------------------------------------------------------------
// Kernel 3: sum NWAVES partials, scale, clamp.
// ---------------------------------------------------------------------------
__global__ __launch_bounds__(256) void finalize_kernel(
    const double* __restrict__ partials, const float* __restrict__ target,
    float* __restrict__ out) {
  __shared__ double red[4];
  double s = 0.0;
  for (int i = threadIdx.x; i < NWAVES; i += 256) s += partials[i];
#pragma unroll
  for (int off = 32; off > 0; off >>= 1) s += __shfl_down(s, off, 64);
  int wave = threadIdx.x >> 6, lane = threadIdx.x & 63;
  if (lane == 0) red[wave] = s;
  __syncthreads();
  if (threadIdx.x == 0) {
    double tot = red[0] + red[1] + red[2] + red[3];
    double mf  = 2.0 * tot / ((double)N * (double)(N - 1) * (double)T);
    double r   = mf - (double)target[0];
    out[0] = (float)(r > 0.0 ? r : 0.0);
  }
}

extern "C" void kernel_launch(void* const* d_in, const int* in_sizes, int n_in,
                              void* d_out, int out_size, void* d_ws, size_t ws_size,
                              hipStream_t stream) {
  const float* target = (const float*)d_in[0];
  const float* pred   = (const float*)d_in[1];
  const float* X      = (const float*)d_in[2];
  // d_in[3] = ntimes (==32, hardcoded); d_in[4] = scale
  const float* scale  = (const float*)d_in[4];

  double*         partials = (double*)d_ws;                          // 33 KB
  unsigned short* hXt = (unsigned short*)((char*)d_ws + (1u << 20)); // 512 KB
  unsigned short* lXt = (unsigned short*)((char*)d_ws + (2u << 20)); // 512 KB

  presplit_kernel<<<dim3(D), dim3(64), 0, stream>>>(X, hXt, lXt);
  pair_kernel<<<dim3(NWAVES), dim3(64), 0, stream>>>(pred, hXt, lXt, scale,
                                                     partials);
  finalize_kernel<<<dim3(1), dim3(256), 0, stream>>>(partials, target,
                                                     (float*)d_out);
}